// Round 1
// baseline (2928.809 us; speedup 1.0000x reference)
//
#include <hip/hip_runtime.h>

// ---------------------------------------------------------------------------
// Seq2Seq: encoder LSTM (128 steps) -> decoder LSTM (127 steps) -> FC to vocab
// B=32, S=T=128, V=32000, E=H=256
//
// Pipeline:
//  1) zero_col0        : out[:,0,:] = 0
//  2) cvt_bf16         : fc_W f32 -> bf16
//  3) xg_gemm (enc/dec): xg[t*32+b][n] = emb[tok]@Wih^T + b   (bf16 MFMA)
//  4) lstm_persistent  : 255 sequential steps, 64 blocks, grid barrier/step,
//                        fp32 vector math, Whh slice resident in LDS
//  5) fc_gemm          : logits = hs @ fc_W^T + fc_b          (bf16 MFMA)
// ---------------------------------------------------------------------------

typedef __attribute__((ext_vector_type(8))) short bf16x8;
typedef __attribute__((ext_vector_type(4))) float f32x4;
typedef __attribute__((ext_vector_type(8))) unsigned short u16x8;

// workspace byte offsets (all 256-aligned)
#define WS_XG_E   0u          // 128*32*1024 f32 = 16,777,216 B
#define WS_XG_D   16777216u   // 127*32*1024 f32 = 16,646,144 B
#define WS_FCW    33423360u   // 32000*256 bf16  = 16,384,000 B
#define WS_HS     49807360u   // 4064*256 bf16   =  2,080,768 B
#define WS_HBUF   51888128u   // 2*32*256 f32    =     65,536 B
#define WS_BAR    51953664u   // counters        =        256 B

__device__ __forceinline__ unsigned short f2bf(float f) {
  unsigned u = __float_as_uint(f);
  u += 0x7FFFu + ((u >> 16) & 1u);   // round-to-nearest-even
  return (unsigned short)(u >> 16);
}

__device__ __forceinline__ float sigf(float x) {
  return 1.f / (1.f + __expf(-x));
}

// ---------------------------------------------------------------------------
__global__ __launch_bounds__(256) void zero_col0(float* __restrict__ out) {
  int i = blockIdx.x * 256 + threadIdx.x;        // 256,000 float4s total
  int b = i / 8000;
  int r = i - b * 8000;
  float4 z; z.x = 0.f; z.y = 0.f; z.z = 0.f; z.w = 0.f;
  ((float4*)out)[b * 1024000 + r] = z;           // out[b][0][v]
}

__global__ __launch_bounds__(256) void cvt_bf16(const float* __restrict__ in,
                                                unsigned short* __restrict__ o,
                                                int n4) {
  int i = blockIdx.x * 256 + threadIdx.x;
  if (i < n4) {
    float4 v = ((const float4*)in)[i];
    ushort4 u;
    u.x = f2bf(v.x); u.y = f2bf(v.y); u.z = f2bf(v.z); u.w = f2bf(v.w);
    *(ushort4*)(o + i * 4) = u;
  }
}

// ---------------------------------------------------------------------------
// xg[row][n] = emb[token(row)] @ Wih^T + bias ; row = t*32 + b
// tokens laid out [B][128]; token(row) = tok[b*128 + t]
// BM=BN=128, K=256 (single LDS load), 4 waves each 64x64, 16x16x32 bf16 MFMA
__global__ __launch_bounds__(256) void xg_gemm(
    const int* __restrict__ tok, const float* __restrict__ emb,
    const float* __restrict__ Wih, const float* __restrict__ bias,
    float* __restrict__ xg, const int Mrows) {
  __shared__ unsigned short As[128][264];  // +8 bf16 pad: 528B stride -> 2-way (free)
  __shared__ unsigned short Bs[128][264];
  const int tid = threadIdx.x;
  const int nb = blockIdx.x, rb = blockIdx.y;
  {
    int lr = tid >> 1, half = tid & 1;
    int cb = half * 128;
    int row = rb * 128 + lr;
    int rowc = row < Mrows ? row : (Mrows - 1);
    int tt = rowc >> 5, bb = rowc & 31;
    int tk = tok[bb * 128 + tt];
    const float4* sa = (const float4*)(emb + tk * 256 + cb);
    const float4* sb = (const float4*)(Wih + (nb * 128 + lr) * 256 + cb);
#pragma unroll
    for (int i = 0; i < 32; ++i) {
      float4 v = sa[i];
      ushort4 u;
      u.x = f2bf(v.x); u.y = f2bf(v.y); u.z = f2bf(v.z); u.w = f2bf(v.w);
      *(ushort4*)&As[lr][cb + i * 4] = u;
      float4 v2 = sb[i];
      ushort4 u2;
      u2.x = f2bf(v2.x); u2.y = f2bf(v2.y); u2.z = f2bf(v2.z); u2.w = f2bf(v2.w);
      *(ushort4*)&Bs[lr][cb + i * 4] = u2;
    }
  }
  __syncthreads();
  const int lane = tid & 63, w = tid >> 6;
  const int wr = w >> 1, wc = w & 1;
  const int fr = lane & 15, kg = lane >> 4;
  f32x4 acc[4][4];
  const f32x4 zero = {0.f, 0.f, 0.f, 0.f};
#pragma unroll
  for (int mi = 0; mi < 4; ++mi)
#pragma unroll
    for (int ni = 0; ni < 4; ++ni) acc[mi][ni] = zero;
#pragma unroll
  for (int ks = 0; ks < 8; ++ks) {
    const int kb = ks * 32 + kg * 8;
    bf16x8 a[4], b[4];
#pragma unroll
    for (int mi = 0; mi < 4; ++mi)
      a[mi] = *(const bf16x8*)&As[wr * 64 + mi * 16 + fr][kb];
#pragma unroll
    for (int ni = 0; ni < 4; ++ni)
      b[ni] = *(const bf16x8*)&Bs[wc * 64 + ni * 16 + fr][kb];
#pragma unroll
    for (int mi = 0; mi < 4; ++mi)
#pragma unroll
      for (int ni = 0; ni < 4; ++ni)
        acc[mi][ni] = __builtin_amdgcn_mfma_f32_16x16x32_bf16(a[mi], b[ni], acc[mi][ni], 0, 0, 0);
  }
#pragma unroll
  for (int ni = 0; ni < 4; ++ni) {
    const int colg = nb * 128 + wc * 64 + ni * 16 + fr;
    const float bv = bias[colg];
#pragma unroll
    for (int mi = 0; mi < 4; ++mi) {
#pragma unroll
      for (int r = 0; r < 4; ++r) {
        int rowg = rb * 128 + wr * 64 + mi * 16 + kg * 4 + r;
        if (rowg < Mrows) xg[rowg * 1024 + colg] = acc[mi][ni][r] + bv;
      }
    }
  }
}

// ---------------------------------------------------------------------------
// Persistent LSTM: 64 blocks x 256 threads. Block owns 4 H-dims (d0..d0+3) ->
// 16 gate rows of Whh in LDS for the whole phase. Per step: stage h (32x256)
// to LDS, compute 16x32 gate dots (fp32, 4r x 4b x kc8 register tiling),
// pointwise LSTM update by 128 threads, device-scope grid barrier.
__global__ __launch_bounds__(256) void lstm_persistent(
    const float* __restrict__ encWhh, const float* __restrict__ decWhh,
    const float* __restrict__ xgE, const float* __restrict__ xgD,
    float* __restrict__ hb, unsigned short* __restrict__ hs,
    unsigned* __restrict__ bar) {
  __shared__ float Ws[16][257];   // pad 257: conflict-free compute reads
  __shared__ float hl[32][257];
  __shared__ float gp[8][16][33];
  const int tid = threadIdx.x;
  const int d0 = blockIdx.x * 4;
  const int bg = tid & 7, rg = (tid >> 3) & 3, kc = tid >> 5;
  const int pb = tid >> 2, pd = tid & 3;   // pointwise (batch, dim) for tid<128
  float c_reg = 0.f;
  unsigned gs = 0;

  for (int phase = 0; phase < 2; ++phase) {
    const float* Whh = phase ? decWhh : encWhh;
    const float* xg = phase ? xgD : xgE;
    const int steps = phase ? 127 : 128;
    {  // load this block's 16 Whh rows (lr = gate*4 + dim)
      int lr = tid >> 4;
      int c0 = (tid & 15) * 16;
      int grow = (lr >> 2) * 256 + d0 + (lr & 3);
      const float* wsrc = Whh + grow * 256 + c0;
#pragma unroll
      for (int j = 0; j < 16; ++j) Ws[lr][c0 + j] = wsrc[j];
    }
    __syncthreads();

    for (int t = 0; t < steps; ++t) {
      // stage full h[32][256] from ping-pong buffer
      const float* hsrc = hb + (gs & 1u) * 8192;
#pragma unroll
      for (int i = 0; i < 32; ++i) {
        int idx = tid + i * 256;
        hl[idx >> 8][idx & 255] = hsrc[idx];
      }
      __syncthreads();

      float acc[4][4];
#pragma unroll
      for (int i = 0; i < 4; ++i)
#pragma unroll
        for (int j = 0; j < 4; ++j) acc[i][j] = 0.f;
      const int kbase = kc * 32;
#pragma unroll 8
      for (int k = kbase; k < kbase + 32; ++k) {
        float w0 = Ws[4 * rg + 0][k], w1 = Ws[4 * rg + 1][k];
        float w2 = Ws[4 * rg + 2][k], w3 = Ws[4 * rg + 3][k];
        float h0 = hl[4 * bg + 0][k], h1 = hl[4 * bg + 1][k];
        float h2 = hl[4 * bg + 2][k], h3 = hl[4 * bg + 3][k];
        acc[0][0] = fmaf(w0, h0, acc[0][0]); acc[0][1] = fmaf(w0, h1, acc[0][1]);
        acc[0][2] = fmaf(w0, h2, acc[0][2]); acc[0][3] = fmaf(w0, h3, acc[0][3]);
        acc[1][0] = fmaf(w1, h0, acc[1][0]); acc[1][1] = fmaf(w1, h1, acc[1][1]);
        acc[1][2] = fmaf(w1, h2, acc[1][2]); acc[1][3] = fmaf(w1, h3, acc[1][3]);
        acc[2][0] = fmaf(w2, h0, acc[2][0]); acc[2][1] = fmaf(w2, h1, acc[2][1]);
        acc[2][2] = fmaf(w2, h2, acc[2][2]); acc[2][3] = fmaf(w2, h3, acc[2][3]);
        acc[3][0] = fmaf(w3, h0, acc[3][0]); acc[3][1] = fmaf(w3, h1, acc[3][1]);
        acc[3][2] = fmaf(w3, h2, acc[3][2]); acc[3][3] = fmaf(w3, h3, acc[3][3]);
      }
#pragma unroll
      for (int i = 0; i < 4; ++i)
#pragma unroll
        for (int j = 0; j < 4; ++j) gp[kc][4 * rg + i][4 * bg + j] = acc[i][j];
      __syncthreads();

      if (tid < 128) {
        const float* xgr = xg + (t * 32 + pb) * 1024 + d0 + pd;
        float g0 = xgr[0], g1 = xgr[256], g2 = xgr[512], g3 = xgr[768];
#pragma unroll
        for (int k2 = 0; k2 < 8; ++k2) {
          g0 += gp[k2][pd][pb];
          g1 += gp[k2][4 + pd][pb];
          g2 += gp[k2][8 + pd][pb];
          g3 += gp[k2][12 + pd][pb];
        }
        float ig = sigf(g0), fg = sigf(g1), gg = tanhf(g2), og = sigf(g3);
        c_reg = fg * c_reg + ig * gg;
        float h = og * tanhf(c_reg);
        hb[((gs + 1u) & 1u) * 8192 + pb * 256 + d0 + pd] = h;
        if (phase) hs[(t * 32 + pb) * 256 + d0 + pd] = f2bf(h);
      }

      // ---- grid barrier (monotonic generation counter) ----
      gs++;
      __syncthreads();
      if (tid == 0) {
        __threadfence();  // write back this XCD's L2 (h slice visible)
        unsigned old = __hip_atomic_fetch_add(&bar[0], 1u, __ATOMIC_ACQ_REL,
                                              __HIP_MEMORY_SCOPE_AGENT);
        if (old + 1u == 64u * gs) {
          __hip_atomic_store(&bar[1], gs, __ATOMIC_RELEASE,
                             __HIP_MEMORY_SCOPE_AGENT);
        } else {
          while (__hip_atomic_load(&bar[1], __ATOMIC_ACQUIRE,
                                   __HIP_MEMORY_SCOPE_AGENT) < gs) {
            __builtin_amdgcn_s_sleep(1);
          }
        }
        __threadfence();  // invalidate caches before reading others' h
      }
      __syncthreads();
    }
  }
}

// ---------------------------------------------------------------------------
// FC: out[b][t+1][v] = hs[t*32+b][:] . fc_W[v][:] + fc_b[v]
__global__ __launch_bounds__(256) void fc_gemm(
    const unsigned short* __restrict__ hsb, const unsigned short* __restrict__ fwb,
    const float* __restrict__ fcb, float* __restrict__ out) {
  __shared__ unsigned short As[128][264];
  __shared__ unsigned short Bs[128][264];
  const int tid = threadIdx.x;
  const int nb = blockIdx.x, rb = blockIdx.y;
  {
    int lr = tid >> 1, half = tid & 1;
    int cb = half * 128;
    int row = rb * 128 + lr;
    if (row < 4064) {
      const u16x8* s = (const u16x8*)(hsb + row * 256 + cb);
#pragma unroll
      for (int i = 0; i < 16; ++i) *(u16x8*)&As[lr][cb + i * 8] = s[i];
    } else {
      u16x8 z = {0, 0, 0, 0, 0, 0, 0, 0};
#pragma unroll
      for (int i = 0; i < 16; ++i) *(u16x8*)&As[lr][cb + i * 8] = z;
    }
    const u16x8* s2 = (const u16x8*)(fwb + (nb * 128 + lr) * 256 + cb);
#pragma unroll
    for (int i = 0; i < 16; ++i) *(u16x8*)&Bs[lr][cb + i * 8] = s2[i];
  }
  __syncthreads();
  const int lane = tid & 63, w = tid >> 6;
  const int wr = w >> 1, wc = w & 1;
  const int fr = lane & 15, kg = lane >> 4;
  f32x4 acc[4][4];
  const f32x4 zero = {0.f, 0.f, 0.f, 0.f};
#pragma unroll
  for (int mi = 0; mi < 4; ++mi)
#pragma unroll
    for (int ni = 0; ni < 4; ++ni) acc[mi][ni] = zero;
#pragma unroll
  for (int ks = 0; ks < 8; ++ks) {
    const int kb = ks * 32 + kg * 8;
    bf16x8 a[4], b[4];
#pragma unroll
    for (int mi = 0; mi < 4; ++mi)
      a[mi] = *(const bf16x8*)&As[wr * 64 + mi * 16 + fr][kb];
#pragma unroll
    for (int ni = 0; ni < 4; ++ni)
      b[ni] = *(const bf16x8*)&Bs[wc * 64 + ni * 16 + fr][kb];
#pragma unroll
    for (int mi = 0; mi < 4; ++mi)
#pragma unroll
      for (int ni = 0; ni < 4; ++ni)
        acc[mi][ni] = __builtin_amdgcn_mfma_f32_16x16x32_bf16(a[mi], b[ni], acc[mi][ni], 0, 0, 0);
  }
#pragma unroll
  for (int ni = 0; ni < 4; ++ni) {
    const int colg = nb * 128 + wc * 64 + ni * 16 + fr;
    const float bv = fcb[colg];
#pragma unroll
    for (int mi = 0; mi < 4; ++mi) {
#pragma unroll
      for (int r = 0; r < 4; ++r) {
        int rowg = rb * 128 + wr * 64 + mi * 16 + kg * 4 + r;
        if (rowg < 4064) {
          int tt = rowg >> 5, bb = rowg & 31;
          out[(bb * 128 + tt + 1) * 32000 + colg] = acc[mi][ni][r] + bv;
        }
      }
    }
  }
}

// ---------------------------------------------------------------------------
extern "C" void kernel_launch(void* const* d_in, const int* in_sizes, int n_in,
                              void* d_out, int out_size, void* d_ws, size_t ws_size,
                              hipStream_t stream) {
  const int* src = (const int*)d_in[0];
  const int* tgt = (const int*)d_in[1];
  const float* enc_emb = (const float*)d_in[2];
  const float* enc_Wih = (const float*)d_in[3];
  const float* enc_Whh = (const float*)d_in[4];
  const float* enc_b = (const float*)d_in[5];
  const float* dec_emb = (const float*)d_in[6];
  const float* dec_Wih = (const float*)d_in[7];
  const float* dec_Whh = (const float*)d_in[8];
  const float* dec_b = (const float*)d_in[9];
  const float* fc_W = (const float*)d_in[10];
  const float* fc_b = (const float*)d_in[11];
  float* out = (float*)d_out;
  char* ws = (char*)d_ws;

  float* xg_e = (float*)(ws + WS_XG_E);
  float* xg_d = (float*)(ws + WS_XG_D);
  unsigned short* fcw = (unsigned short*)(ws + WS_FCW);
  unsigned short* hs = (unsigned short*)(ws + WS_HS);
  float* hbuf = (float*)(ws + WS_HBUF);
  unsigned* bar = (unsigned*)(ws + WS_BAR);

  // zero h ping-pong (h0=c0=0) + barrier counters, every call (deterministic)
  hipMemsetAsync(ws + WS_HBUF, 0, 65536 + 256, stream);

  zero_col0<<<1000, 256, 0, stream>>>(out);
  cvt_bf16<<<8000, 256, 0, stream>>>(fc_W, fcw, 2048000);
  xg_gemm<<<dim3(8, 32), 256, 0, stream>>>(src, enc_emb, enc_Wih, enc_b, xg_e, 4096);
  xg_gemm<<<dim3(8, 32), 256, 0, stream>>>(tgt, dec_emb, dec_Wih, dec_b, xg_d, 4064);
  lstm_persistent<<<64, 256, 0, stream>>>(enc_Whh, dec_Whh, xg_e, xg_d, hbuf, hs, bar);
  fc_gemm<<<dim3(250, 32), 256, 0, stream>>>(hs, fcw, fc_b, out);
}

// Round 2
// 2452.314 us; speedup vs baseline: 1.1943x; 1.1943x over previous
//
#include <hip/hip_runtime.h>

// ---------------------------------------------------------------------------
// Seq2Seq: encoder LSTM (128 steps) -> decoder LSTM (127 steps) -> FC to vocab
// B=32, S=T=128, V=32000, E=H=256
//
// Pipeline:
//  1) zero_col0   : out[:,0,:] = 0
//  2) cvt_bf16    : fc_W f32 -> bf16
//  3) prep_wf     : Whh (enc,dec) -> transposed [64 k4][1024 r][float4] layout
//  4) xg_gemm x2  : xg = emb[tok]@Wih^T + b   (bf16 MFMA, all timesteps)
//  5) lstm_batch  : 32 blocks (one per batch row) x 1024 thr; 255 serial steps
//                   entirely block-local (h in LDS, c in regs, NO grid sync)
//  6) fc_gemm     : logits = hs @ fc_W^T + fc_b  (bf16 MFMA)
// ---------------------------------------------------------------------------

typedef __attribute__((ext_vector_type(8))) short bf16x8;
typedef __attribute__((ext_vector_type(4))) float f32x4;
typedef __attribute__((ext_vector_type(8))) unsigned short u16x8;

// workspace byte offsets (all 256-aligned)
#define WS_XG_E   0u          // 128*32*1024 f32 = 16,777,216 B
#define WS_XG_D   16777216u   // 127*32*1024 f32 = 16,646,144 B
#define WS_FCW    33423360u   // 32000*256 bf16  = 16,384,000 B
#define WS_HS     49807360u   // 4064*256 bf16   =  2,080,768 B
#define WS_WTE    51888128u   // 1024*256 f32    =  1,048,576 B
#define WS_WTD    52936704u   // 1024*256 f32    =  1,048,576 B

__device__ __forceinline__ unsigned short f2bf(float f) {
  unsigned u = __float_as_uint(f);
  u += 0x7FFFu + ((u >> 16) & 1u);   // round-to-nearest-even
  return (unsigned short)(u >> 16);
}

__device__ __forceinline__ float sigf(float x) {
  float e = __expf(-x);
  return __builtin_amdgcn_rcpf(1.f + e);
}
__device__ __forceinline__ float tanh_fast(float x) {
  float e = __expf(-2.f * x);
  return fmaf(2.f, __builtin_amdgcn_rcpf(1.f + e), -1.f);  // (1-e)/(1+e)
}

// ---------------------------------------------------------------------------
__global__ __launch_bounds__(256) void zero_col0(float* __restrict__ out) {
  int i = blockIdx.x * 256 + threadIdx.x;        // 256,000 float4s total
  int b = i / 8000;
  int r = i - b * 8000;
  float4 z; z.x = 0.f; z.y = 0.f; z.z = 0.f; z.w = 0.f;
  ((float4*)out)[b * 1024000 + r] = z;           // out[b][0][v]
}

__global__ __launch_bounds__(256) void cvt_bf16(const float* __restrict__ in,
                                                unsigned short* __restrict__ o,
                                                int n4) {
  int i = blockIdx.x * 256 + threadIdx.x;
  if (i < n4) {
    float4 v = ((const float4*)in)[i];
    ushort4 u;
    u.x = f2bf(v.x); u.y = f2bf(v.y); u.z = f2bf(v.z); u.w = f2bf(v.w);
    *(ushort4*)(o + i * 4) = u;
  }
}

// Whh[1024 r][256 k] -> WT[k4][1024 r][4] floats: dst[((k4*1024)+r)*4+m] =
// Whh[r*256 + 4*k4 + m]. Wave loads of WT are 1KB contiguous (lane = r).
__global__ __launch_bounds__(256) void prep_wf(const float* __restrict__ We,
                                               const float* __restrict__ Wd,
                                               float* __restrict__ Te,
                                               float* __restrict__ Td) {
  int d = blockIdx.x * 256 + threadIdx.x;       // 0..262143
  const float* W = blockIdx.y ? Wd : We;
  float* T = blockIdx.y ? Td : Te;
  int k4 = d >> 12, r = (d >> 2) & 1023, m = d & 3;
  T[d] = W[r * 256 + k4 * 4 + m];
}

// ---------------------------------------------------------------------------
// xg[row][n] = emb[token(row)] @ Wih^T + bias ; row = t*32 + b
__global__ __launch_bounds__(256) void xg_gemm(
    const int* __restrict__ tok, const float* __restrict__ emb,
    const float* __restrict__ Wih, const float* __restrict__ bias,
    float* __restrict__ xg, const int Mrows) {
  __shared__ unsigned short As[128][264];  // +8 bf16 pad -> 2-way (free)
  __shared__ unsigned short Bs[128][264];
  const int tid = threadIdx.x;
  const int nb = blockIdx.x, rb = blockIdx.y;
  {
    int lr = tid >> 1, half = tid & 1;
    int cb = half * 128;
    int row = rb * 128 + lr;
    int rowc = row < Mrows ? row : (Mrows - 1);
    int tt = rowc >> 5, bb = rowc & 31;
    int tk = tok[bb * 128 + tt];
    const float4* sa = (const float4*)(emb + tk * 256 + cb);
    const float4* sb = (const float4*)(Wih + (nb * 128 + lr) * 256 + cb);
#pragma unroll
    for (int i = 0; i < 32; ++i) {
      float4 v = sa[i];
      ushort4 u;
      u.x = f2bf(v.x); u.y = f2bf(v.y); u.z = f2bf(v.z); u.w = f2bf(v.w);
      *(ushort4*)&As[lr][cb + i * 4] = u;
      float4 v2 = sb[i];
      ushort4 u2;
      u2.x = f2bf(v2.x); u2.y = f2bf(v2.y); u2.z = f2bf(v2.z); u2.w = f2bf(v2.w);
      *(ushort4*)&Bs[lr][cb + i * 4] = u2;
    }
  }
  __syncthreads();
  const int lane = tid & 63, w = tid >> 6;
  const int wr = w >> 1, wc = w & 1;
  const int fr = lane & 15, kg = lane >> 4;
  f32x4 acc[4][4];
  const f32x4 zero = {0.f, 0.f, 0.f, 0.f};
#pragma unroll
  for (int mi = 0; mi < 4; ++mi)
#pragma unroll
    for (int ni = 0; ni < 4; ++ni) acc[mi][ni] = zero;
#pragma unroll
  for (int ks = 0; ks < 8; ++ks) {
    const int kb = ks * 32 + kg * 8;
    bf16x8 a[4], b[4];
#pragma unroll
    for (int mi = 0; mi < 4; ++mi)
      a[mi] = *(const bf16x8*)&As[wr * 64 + mi * 16 + fr][kb];
#pragma unroll
    for (int ni = 0; ni < 4; ++ni)
      b[ni] = *(const bf16x8*)&Bs[wc * 64 + ni * 16 + fr][kb];
#pragma unroll
    for (int mi = 0; mi < 4; ++mi)
#pragma unroll
      for (int ni = 0; ni < 4; ++ni)
        acc[mi][ni] = __builtin_amdgcn_mfma_f32_16x16x32_bf16(a[mi], b[ni], acc[mi][ni], 0, 0, 0);
  }
#pragma unroll
  for (int ni = 0; ni < 4; ++ni) {
    const int colg = nb * 128 + wc * 64 + ni * 16 + fr;
    const float bv = bias[colg];
#pragma unroll
    for (int mi = 0; mi < 4; ++mi) {
#pragma unroll
      for (int r = 0; r < 4; ++r) {
        int rowg = rb * 128 + wr * 64 + mi * 16 + kg * 4 + r;
        if (rowg < Mrows) xg[rowg * 1024 + colg] = acc[mi][ni][r] + bv;
      }
    }
  }
}

// ---------------------------------------------------------------------------
// Per-batch LSTM chain. Block b: thread r (0..1023) owns gate row r.
// Per step: g[r] = dot(WT[.][r], h[.]) (h = LDS broadcast reads), exchange
// via glds, 256 threads do pointwise + write h (LDS) / hs (global, decoder).
__global__ __launch_bounds__(1024) void lstm_batch(
    const float* __restrict__ WTe, const float* __restrict__ WTd,
    const float* __restrict__ xgE, const float* __restrict__ xgD,
    unsigned short* __restrict__ hs) {
  __shared__ __align__(16) float hlds[256];
  __shared__ float glds[1024];
  const int tid = threadIdx.x;
  const int b = blockIdx.x;
  float c = 0.f;
  if (tid < 256) hlds[tid] = 0.f;

  for (int phase = 0; phase < 2; ++phase) {
    const float4* WT = (const float4*)(phase ? WTd : WTe);
    const float* xg = phase ? xgD : xgE;
    const int steps = phase ? 127 : 128;
    const float4* wp = WT + tid;                 // + k4*1024 per k-quad
    for (int t = 0; t < steps; ++t) {
      __syncthreads();                           // h from prev step visible
      float x0, x1, x2, x3;
      if (tid < 256) {                           // prefetch xg (used post-sync)
        const float* xr = xg + (t * 32 + b) * 1024 + tid;
        x0 = xr[0]; x1 = xr[256]; x2 = xr[512]; x3 = xr[768];
      }
      const float4* hp = (const float4*)hlds;
      float g0 = 0.f, g1 = 0.f, g2 = 0.f, g3 = 0.f;
#pragma unroll 16
      for (int k4 = 0; k4 < 64; ++k4) {
        float4 w = wp[k4 * 1024];
        float4 hv = hp[k4];                      // wave-uniform -> broadcast
        g0 = fmaf(w.x, hv.x, g0);
        g1 = fmaf(w.y, hv.y, g1);
        g2 = fmaf(w.z, hv.z, g2);
        g3 = fmaf(w.w, hv.w, g3);
      }
      glds[tid] = (g0 + g1) + (g2 + g3);
      __syncthreads();                           // all reads of hlds done too
      if (tid < 256) {
        float gi = x0 + glds[tid];
        float gf = x1 + glds[256 + tid];
        float gg = x2 + glds[512 + tid];
        float go = x3 + glds[768 + tid];
        c = sigf(gf) * c + sigf(gi) * tanh_fast(gg);
        float h = sigf(go) * tanh_fast(c);
        hlds[tid] = h;
        if (phase) hs[(t * 32 + b) * 256 + tid] = f2bf(h);
      }
    }
  }
}

// ---------------------------------------------------------------------------
// FC: out[b][t+1][v] = hs[t*32+b][:] . fc_W[v][:] + fc_b[v]
__global__ __launch_bounds__(256) void fc_gemm(
    const unsigned short* __restrict__ hsb, const unsigned short* __restrict__ fwb,
    const float* __restrict__ fcb, float* __restrict__ out) {
  __shared__ unsigned short As[128][264];
  __shared__ unsigned short Bs[128][264];
  const int tid = threadIdx.x;
  const int nb = blockIdx.x, rb = blockIdx.y;
  {
    int lr = tid >> 1, half = tid & 1;
    int cb = half * 128;
    int row = rb * 128 + lr;
    if (row < 4064) {
      const u16x8* s = (const u16x8*)(hsb + row * 256 + cb);
#pragma unroll
      for (int i = 0; i < 16; ++i) *(u16x8*)&As[lr][cb + i * 8] = s[i];
    } else {
      u16x8 z = {0, 0, 0, 0, 0, 0, 0, 0};
#pragma unroll
      for (int i = 0; i < 16; ++i) *(u16x8*)&As[lr][cb + i * 8] = z;
    }
    const u16x8* s2 = (const u16x8*)(fwb + (nb * 128 + lr) * 256 + cb);
#pragma unroll
    for (int i = 0; i < 16; ++i) *(u16x8*)&Bs[lr][cb + i * 8] = s2[i];
  }
  __syncthreads();
  const int lane = tid & 63, w = tid >> 6;
  const int wr = w >> 1, wc = w & 1;
  const int fr = lane & 15, kg = lane >> 4;
  f32x4 acc[4][4];
  const f32x4 zero = {0.f, 0.f, 0.f, 0.f};
#pragma unroll
  for (int mi = 0; mi < 4; ++mi)
#pragma unroll
    for (int ni = 0; ni < 4; ++ni) acc[mi][ni] = zero;
#pragma unroll
  for (int ks = 0; ks < 8; ++ks) {
    const int kb = ks * 32 + kg * 8;
    bf16x8 a[4], b[4];
#pragma unroll
    for (int mi = 0; mi < 4; ++mi)
      a[mi] = *(const bf16x8*)&As[wr * 64 + mi * 16 + fr][kb];
#pragma unroll
    for (int ni = 0; ni < 4; ++ni)
      b[ni] = *(const bf16x8*)&Bs[wc * 64 + ni * 16 + fr][kb];
#pragma unroll
    for (int mi = 0; mi < 4; ++mi)
#pragma unroll
      for (int ni = 0; ni < 4; ++ni)
        acc[mi][ni] = __builtin_amdgcn_mfma_f32_16x16x32_bf16(a[mi], b[ni], acc[mi][ni], 0, 0, 0);
  }
#pragma unroll
  for (int ni = 0; ni < 4; ++ni) {
    const int colg = nb * 128 + wc * 64 + ni * 16 + fr;
    const float bv = fcb[colg];
#pragma unroll
    for (int mi = 0; mi < 4; ++mi) {
#pragma unroll
      for (int r = 0; r < 4; ++r) {
        int rowg = rb * 128 + wr * 64 + mi * 16 + kg * 4 + r;
        if (rowg < 4064) {
          int tt = rowg >> 5, bb = rowg & 31;
          out[(bb * 128 + tt + 1) * 32000 + colg] = acc[mi][ni][r] + bv;
        }
      }
    }
  }
}

// ---------------------------------------------------------------------------
extern "C" void kernel_launch(void* const* d_in, const int* in_sizes, int n_in,
                              void* d_out, int out_size, void* d_ws, size_t ws_size,
                              hipStream_t stream) {
  const int* src = (const int*)d_in[0];
  const int* tgt = (const int*)d_in[1];
  const float* enc_emb = (const float*)d_in[2];
  const float* enc_Wih = (const float*)d_in[3];
  const float* enc_Whh = (const float*)d_in[4];
  const float* enc_b = (const float*)d_in[5];
  const float* dec_emb = (const float*)d_in[6];
  const float* dec_Wih = (const float*)d_in[7];
  const float* dec_Whh = (const float*)d_in[8];
  const float* dec_b = (const float*)d_in[9];
  const float* fc_W = (const float*)d_in[10];
  const float* fc_b = (const float*)d_in[11];
  float* out = (float*)d_out;
  char* ws = (char*)d_ws;

  float* xg_e = (float*)(ws + WS_XG_E);
  float* xg_d = (float*)(ws + WS_XG_D);
  unsigned short* fcw = (unsigned short*)(ws + WS_FCW);
  unsigned short* hs = (unsigned short*)(ws + WS_HS);
  float* wte = (float*)(ws + WS_WTE);
  float* wtd = (float*)(ws + WS_WTD);

  zero_col0<<<1000, 256, 0, stream>>>(out);
  cvt_bf16<<<8000, 256, 0, stream>>>(fc_W, fcw, 2048000);
  prep_wf<<<dim3(1024, 2), 256, 0, stream>>>(enc_Whh, dec_Whh, wte, wtd);
  xg_gemm<<<dim3(8, 32), 256, 0, stream>>>(src, enc_emb, enc_Wih, enc_b, xg_e, 4096);
  xg_gemm<<<dim3(8, 32), 256, 0, stream>>>(tgt, dec_emb, dec_Wih, dec_b, xg_d, 4064);
  lstm_batch<<<32, 1024, 0, stream>>>(wte, wtd, xg_e, xg_d, hs);
  fc_gemm<<<dim3(250, 32), 256, 0, stream>>>(hs, fcw, fc_b, out);
}